// Round 3
// baseline (1065.617 us; speedup 1.0000x reference)
//
#include <hip/hip_runtime.h>
#include <cstdint>
#include <cstddef>

typedef unsigned short u16;
typedef __bf16 bf16x8 __attribute__((ext_vector_type(8)));
typedef float f32x4 __attribute__((ext_vector_type(4)));

// ---------- helpers ----------
__device__ __forceinline__ u16 f2bf(float f) {            // round-to-nearest-even
  unsigned u = __float_as_uint(f);
  u += 0x7fffu + ((u >> 16) & 1u);
  return (u16)(u >> 16);
}

__device__ __forceinline__ float block_sum(float v, float* sbuf, int tid) {
#pragma unroll
  for (int off = 1; off < 64; off <<= 1) v += __shfl_xor(v, off, 64);
  if ((tid & 63) == 0) sbuf[tid >> 6] = v;
  __syncthreads();
  v = sbuf[0] + sbuf[1] + sbuf[2] + sbuf[3];
  __syncthreads();
  return v;
}

// async global->LDS, 16B per lane (used only by the big-grid GEMM where the
// access pattern is row-chunked; lane-contiguous enough at 3-4 blocks/CU).
__device__ __forceinline__ void gld16(const void* g, void* l) {
  __builtin_amdgcn_global_load_lds((const __attribute__((address_space(1))) void*)g,
                                   (__attribute__((address_space(3))) void*)l,
                                   16, 0, 0);
}

// ---------- epilogue shared by both GEMMs ----------
__device__ __forceinline__ void gemm_epilogue(
    f32x4 (&acc)[4][4], const float* bias, const float* res, void* out,
    int ldc, int m0, int n0, int wm, int wn, int l15, int g, int mode)
{
  float* outF = (float*)out;
  u16* outU = (u16*)out;
#pragma unroll
  for (int i = 0; i < 4; i++) {
#pragma unroll
    for (int j = 0; j < 4; j++) {
      const int col = n0 + wn + j * 16 + l15;
#pragma unroll
      for (int r = 0; r < 4; r++) {
        const int gm = m0 + wm + i * 16 + g * 4 + r;
        const size_t idx = (size_t)gm * ldc + col;
        float v = acc[i][j][r];
        if (mode == 0) {
          if (bias) v += bias[col];
          if (res)  v += res[idx];
          outF[idx] = v;
        } else if (mode == 1) {
          outU[idx] = f2bf(v);
        } else {
          v += bias[col];
          v = 0.5f * v * (1.0f + erff(v * 0.70710678118654752f));
          outU[idx] = f2bf(v);
        }
      }
    }
  }
}

// ---------- big-grid NT GEMM (128x128 tile, BK=32, gld16 staging) ----------
// used for qkv / ffn_in where grid >= 768 blocks (3-4 blocks/CU hide latency)
__global__ __launch_bounds__(256) void gemm_nt(
    const u16* __restrict__ A, const u16* __restrict__ B,
    const float* __restrict__ bias, const float* __restrict__ res,
    void* __restrict__ out, int ldc, int M, int N, int K, int mode)
{
  __shared__ __align__(16) u16 As[128 * 32];
  __shared__ __align__(16) u16 Bs[128 * 32];
  const int tid = threadIdx.x;
  const int m0 = blockIdx.y * 128, n0 = blockIdx.x * 128;
  const int lane = tid & 63, wave = tid >> 6;
  const int l15 = lane & 15, g = (lane >> 4) & 3;
  const int wm = (wave >> 1) * 64, wn = (wave & 1) * 64;

  const int c0 = tid, c1 = tid + 256;
  const int ar0 = c0 >> 2, ak0 = (c0 & 3) * 8;
  const int ar1 = c1 >> 2, ak1 = (c1 & 3) * 8;
  const size_t aoff0 = (size_t)(m0 + ar0) * K + ak0;
  const size_t aoff1 = (size_t)(m0 + ar1) * K + ak1;
  const size_t boff0 = (size_t)(n0 + ar0) * K + ak0;
  const size_t boff1 = (size_t)(n0 + ar1) * K + ak1;

  f32x4 acc[4][4] = {};

  for (int k0 = 0; k0 < K; k0 += 32) {
    gld16(A + aoff0 + k0, As + (size_t)c0 * 8);
    gld16(A + aoff1 + k0, As + (size_t)c1 * 8);
    gld16(B + boff0 + k0, Bs + (size_t)c0 * 8);
    gld16(B + boff1 + k0, Bs + (size_t)c1 * 8);
    __syncthreads();
    bf16x8 af[4], bg[4];
#pragma unroll
    for (int i = 0; i < 4; i++) {
      af[i] = *(const bf16x8*)(As + (wm + i * 16 + l15) * 32 + g * 8);
      bg[i] = *(const bf16x8*)(Bs + (wn + i * 16 + l15) * 32 + g * 8);
    }
#pragma unroll
    for (int i = 0; i < 4; i++)
#pragma unroll
      for (int j = 0; j < 4; j++)
        acc[i][j] = __builtin_amdgcn_mfma_f32_16x16x32_bf16(af[i], bg[j], acc[i][j], 0, 0, 0);
    __syncthreads();
  }
  gemm_epilogue(acc, bias, res, out, ldc, m0, n0, wm, wn, l15, g, mode);
}

// ---------- small-grid NT GEMM (128x128 tile, BK=128, reg-prefetch pipeline) ----------
// for 256-512 block GEMMs: 4x fewer barriers, next-tile loads overlap compute.
__global__ __launch_bounds__(256, 2) void gemm_k128(
    const u16* __restrict__ A, const u16* __restrict__ B,
    const float* __restrict__ bias, const float* __restrict__ res,
    void* __restrict__ out, int ldc, int M, int N, int K, int mode)
{
  __shared__ __align__(16) u16 As[128 * 136];   // +8 pad: uniform bank spread
  __shared__ __align__(16) u16 Bs[128 * 136];
  const int tid = threadIdx.x;
  const int m0 = blockIdx.y * 128, n0 = blockIdx.x * 128;
  const int lane = tid & 63, wave = tid >> 6;
  const int l15 = lane & 15, g = (lane >> 4) & 3;
  const int wm = (wave >> 1) * 64, wn = (wave & 1) * 64;

  const u16* Ap = A + (size_t)m0 * K;
  const u16* Bp = B + (size_t)n0 * K;

  ulong2 ra[8], rb[8];
#pragma unroll
  for (int i = 0; i < 8; ++i) {
    const int q = tid + i * 256, row = q >> 4, cc = q & 15;
    ra[i] = *(const ulong2*)(Ap + (size_t)row * K + cc * 8);
    rb[i] = *(const ulong2*)(Bp + (size_t)row * K + cc * 8);
  }

  f32x4 acc[4][4] = {};

  for (int kb = 0; kb < K; kb += 128) {
    __syncthreads();
#pragma unroll
    for (int i = 0; i < 8; ++i) {
      const int q = tid + i * 256, row = q >> 4, cc = q & 15;
      *(ulong2*)(As + row * 136 + cc * 8) = ra[i];
      *(ulong2*)(Bs + row * 136 + cc * 8) = rb[i];
    }
    __syncthreads();
    if (kb + 128 < K) {
#pragma unroll
      for (int i = 0; i < 8; ++i) {
        const int q = tid + i * 256, row = q >> 4, cc = q & 15;
        ra[i] = *(const ulong2*)(Ap + (size_t)row * K + kb + 128 + cc * 8);
        rb[i] = *(const ulong2*)(Bp + (size_t)row * K + kb + 128 + cc * 8);
      }
    }
#pragma unroll
    for (int kt = 0; kt < 4; ++kt) {
      bf16x8 af[4], bg[4];
#pragma unroll
      for (int i = 0; i < 4; ++i) {
        af[i] = *(const bf16x8*)(As + (wm + i * 16 + l15) * 136 + kt * 32 + g * 8);
        bg[i] = *(const bf16x8*)(Bs + (wn + i * 16 + l15) * 136 + kt * 32 + g * 8);
      }
#pragma unroll
      for (int i = 0; i < 4; i++)
#pragma unroll
        for (int j = 0; j < 4; j++)
          acc[i][j] = __builtin_amdgcn_mfma_f32_16x16x32_bf16(af[i], bg[j], acc[i][j], 0, 0, 0);
    }
  }
  gemm_epilogue(acc, bias, res, out, ldc, m0, n0, wm, wn, l15, g, mode);
}

// ---------- fused flash attention, per-wave row ownership ----------
// qh [64][1024][64] bf16 (pre-scaled 1/8), kh [64][1024][64], vht [64][64][1024]
// ctx out [4][1024][1024] bf16 (merged heads). grid (8 m-tiles, 64 z). 256 thr.
// Each wave owns 32 Q-rows end-to-end: softmax state in registers, no
// cross-wave reductions; 2 barriers/iter; staged via reg-prefetch (coalesced).
__global__ __launch_bounds__(256, 2) void flash_attn(
    const u16* __restrict__ qh, const u16* __restrict__ kh, const u16* __restrict__ vht,
    const float* __restrict__ emask, u16* __restrict__ ctx, int causal)
{
  __shared__ __align__(16) u16 sK[128 * 72];    // [t][d+pad]   18.4 KB
  __shared__ __align__(16) u16 sV[64 * 136];    // [d][t+pad]   17.4 KB
  __shared__ __align__(16) u16 sP[128 * 136];   // [row][t+pad] 34.8 KB

  const int tid = threadIdx.x, lane = tid & 63, wave = tid >> 6;
  const int l15 = lane & 15, g = (lane >> 4) & 3;
  const int z = blockIdx.y, b = z >> 4, h = z & 15;
  const int m0 = blockIdx.x * 128;
  const int r0 = wave * 32;                     // wave's row stripe

  // Q fragments (rows r0..r0+31, d 0..63) register-resident
  bf16x8 qf[2][2];
  {
    const u16* qz = qh + ((size_t)z * 1024 + m0 + r0 + l15) * 64 + g * 8;
#pragma unroll
    for (int i2 = 0; i2 < 2; ++i2)
#pragma unroll
      for (int kc = 0; kc < 2; ++kc)
        qf[i2][kc] = *(const bf16x8*)(qz + (size_t)i2 * 16 * 64 + kc * 32);
  }

  float m_i[2][4], l_i[2][4];
#pragma unroll
  for (int i2 = 0; i2 < 2; ++i2)
#pragma unroll
    for (int r = 0; r < 4; ++r) { m_i[i2][r] = -1.0e30f; l_i[i2][r] = 0.0f; }

  f32x4 o[2][4] = {};
  const int tmax = causal ? m0 : 896;

  // preload first KV tile into registers (lane-contiguous global reads)
  ulong2 kreg[4], vreg[4];
  {
    const u16* kb_ = kh + (size_t)z * 65536;
    const u16* vb_ = vht + (size_t)z * 65536;
#pragma unroll
    for (int i = 0; i < 4; ++i) {
      const int q = tid + i * 256;
      kreg[i] = *(const ulong2*)(kb_ + (size_t)(q >> 3) * 64 + (q & 7) * 8);
      vreg[i] = *(const ulong2*)(vb_ + (size_t)(q >> 4) * 1024 + (q & 15) * 8);
    }
  }

  for (int t0 = 0; t0 <= tmax; t0 += 128) {
    __syncthreads();                            // prev iter done reading sK/sV
#pragma unroll
    for (int i = 0; i < 4; ++i) {
      const int q = tid + i * 256;
      *(ulong2*)(sK + (q >> 3) * 72 + (q & 7) * 8) = kreg[i];
      *(ulong2*)(sV + (q >> 4) * 136 + (q & 15) * 8) = vreg[i];
    }
    __syncthreads();
    if (t0 + 128 <= tmax) {                     // prefetch next tile (hidden under compute)
      const u16* kb_ = kh + (size_t)z * 65536 + (size_t)(t0 + 128) * 64;
      const u16* vb_ = vht + (size_t)z * 65536 + (t0 + 128);
#pragma unroll
      for (int i = 0; i < 4; ++i) {
        const int q = tid + i * 256;
        kreg[i] = *(const ulong2*)(kb_ + (size_t)(q >> 3) * 64 + (q & 7) * 8);
        vreg[i] = *(const ulong2*)(vb_ + (size_t)(q >> 4) * 1024 + (q & 15) * 8);
      }
    }

    // ---- S = Q K^T : rows [r0,r0+32) x cols 0..127 ----
    f32x4 sa[2][8] = {};
#pragma unroll
    for (int kc = 0; kc < 2; ++kc) {
      bf16x8 bg[8];
#pragma unroll
      for (int jn = 0; jn < 8; ++jn)
        bg[jn] = *(const bf16x8*)(sK + (jn * 16 + l15) * 72 + kc * 32 + g * 8);
#pragma unroll
      for (int i2 = 0; i2 < 2; ++i2)
#pragma unroll
        for (int jn = 0; jn < 8; ++jn)
          sa[i2][jn] = __builtin_amdgcn_mfma_f32_16x16x32_bf16(qf[i2][kc], bg[jn], sa[i2][jn], 0, 0, 0);
    }

    // ---- mask ----
    if (causal) {
      if (t0 == m0) {                           // only the diagonal tile
#pragma unroll
        for (int i2 = 0; i2 < 2; ++i2)
#pragma unroll
          for (int jn = 0; jn < 8; ++jn) {
            const int col = jn * 16 + l15;
#pragma unroll
            for (int r = 0; r < 4; ++r) {
              const int row = r0 + i2 * 16 + g * 4 + r;
              if (col > row) sa[i2][jn][r] = -3.0e38f;
            }
          }
      }
    } else {
#pragma unroll
      for (int jn = 0; jn < 8; ++jn) {
        const float mv = emask[(size_t)b * 1024 + t0 + jn * 16 + l15];
#pragma unroll
        for (int i2 = 0; i2 < 2; ++i2)
#pragma unroll
          for (int r = 0; r < 4; ++r) sa[i2][jn][r] += mv;
      }
    }

    // ---- in-wave online softmax (state in registers) ----
    float alpha[2][4];
#pragma unroll
    for (int i2 = 0; i2 < 2; ++i2)
#pragma unroll
      for (int r = 0; r < 4; ++r) {
        float v = sa[i2][0][r];
#pragma unroll
        for (int jn = 1; jn < 8; ++jn) v = fmaxf(v, sa[i2][jn][r]);
        v = fmaxf(v, __shfl_xor(v, 1, 64));
        v = fmaxf(v, __shfl_xor(v, 2, 64));
        v = fmaxf(v, __shfl_xor(v, 4, 64));
        v = fmaxf(v, __shfl_xor(v, 8, 64));
        const float mo = m_i[i2][r];
        const float mn = fmaxf(mo, v);
        m_i[i2][r] = mn;
        alpha[i2][r] = __expf(mo - mn);         // first iter: exp(-1e30-mn) -> 0
        float s = 0.0f;
#pragma unroll
        for (int jn = 0; jn < 8; ++jn) {
          const float p = __expf(sa[i2][jn][r] - mn);
          s += p;
          sP[(r0 + i2 * 16 + g * 4 + r) * 136 + jn * 16 + l15] = f2bf(p);
        }
        s += __shfl_xor(s, 1, 64);
        s += __shfl_xor(s, 2, 64);
        s += __shfl_xor(s, 4, 64);
        s += __shfl_xor(s, 8, 64);
        l_i[i2][r] = alpha[i2][r] * l_i[i2][r] + s;
      }

    // ---- O = alpha*O + P V (own rows only: no barrier, just LDS drain) ----
#pragma unroll
    for (int i2 = 0; i2 < 2; ++i2)
#pragma unroll
      for (int jn = 0; jn < 4; ++jn)
#pragma unroll
        for (int r = 0; r < 4; ++r)
          o[i2][jn][r] *= alpha[i2][r];

    asm volatile("s_waitcnt lgkmcnt(0)" ::: "memory");   // own P writes visible
#pragma unroll
    for (int kc = 0; kc < 4; ++kc) {
      bf16x8 pa[2], vb[4];
#pragma unroll
      for (int i2 = 0; i2 < 2; ++i2)
        pa[i2] = *(const bf16x8*)(sP + (r0 + i2 * 16 + l15) * 136 + kc * 32 + g * 8);
#pragma unroll
      for (int jn = 0; jn < 4; ++jn)
        vb[jn] = *(const bf16x8*)(sV + (jn * 16 + l15) * 136 + kc * 32 + g * 8);
#pragma unroll
      for (int i2 = 0; i2 < 2; ++i2)
#pragma unroll
        for (int jn = 0; jn < 4; ++jn)
          o[i2][jn] = __builtin_amdgcn_mfma_f32_16x16x32_bf16(pa[i2], vb[jn], o[i2][jn], 0, 0, 0);
    }
  }

  // ---- epilogue: O / l, merged-heads ctx ----
#pragma unroll
  for (int i2 = 0; i2 < 2; ++i2)
#pragma unroll
    for (int r = 0; r < 4; ++r) {
      const float inv = 1.0f / l_i[i2][r];
      const size_t base = ((size_t)(b * 1024 + m0 + r0 + i2 * 16 + g * 4 + r)) * 1024 + h * 64;
#pragma unroll
      for (int jn = 0; jn < 4; ++jn)
        ctx[base + jn * 16 + l15] = f2bf(o[i2][jn][r] * inv);
    }
}

// ---------- layernorm (row=1024) -> bf16 ----------
__global__ __launch_bounds__(256) void ln_kernel(const float* __restrict__ x,
    const float* __restrict__ w, const float* __restrict__ b, u16* __restrict__ out)
{
  __shared__ float sbuf[4];
  const int row = blockIdx.x, tid = threadIdx.x;
  const float4 v = *(const float4*)(x + (size_t)row * 1024 + tid * 4);
  float s = block_sum(v.x + v.y + v.z + v.w, sbuf, tid);
  const float u = s * (1.0f / 1024.0f);
  const float d0 = v.x - u, d1 = v.y - u, d2 = v.z - u, d3 = v.w - u;
  float sq = block_sum(d0 * d0 + d1 * d1 + d2 * d2 + d3 * d3, sbuf, tid);
  const float rstd = rsqrtf(sq * (1.0f / 1024.0f) + 1e-12f);
  const int c = tid * 4;
  ushort4 o;
  o.x = f2bf(w[c + 0] * d0 * rstd + b[c + 0]);
  o.y = f2bf(w[c + 1] * d1 * rstd + b[c + 1]);
  o.z = f2bf(w[c + 2] * d2 * rstd + b[c + 2]);
  o.w = f2bf(w[c + 3] * d3 * rstd + b[c + 3]);
  *(ushort4*)(out + (size_t)row * 1024 + c) = o;
}

// ---------- weight fp32[K,N] -> bf16 transposed [N,K] ----------
__global__ __launch_bounds__(256) void wconv_kernel(const float* __restrict__ w,
    u16* __restrict__ wt, int K, int N)
{
  __shared__ float t[32][33];
  const int n0 = blockIdx.x * 32, k0 = blockIdx.y * 32;
  const int tx = threadIdx.x & 31, ty = threadIdx.x >> 5;
#pragma unroll
  for (int r = ty; r < 32; r += 8) t[r][tx] = w[(size_t)(k0 + r) * N + n0 + tx];
  __syncthreads();
#pragma unroll
  for (int r = ty; r < 32; r += 8) wt[(size_t)(n0 + r) * K + k0 + tx] = f2bf(t[tx][r]);
}

// ---------- fp32 -> bf16 elementwise ----------
__global__ __launch_bounds__(256) void cvt_kernel(const float* __restrict__ in, u16* __restrict__ out) {
  const size_t i = ((size_t)blockIdx.x * 256 + threadIdx.x) * 4;
  const float4 v = *(const float4*)(in + i);
  ushort4 o; o.x = f2bf(v.x); o.y = f2bf(v.y); o.z = f2bf(v.z); o.w = f2bf(v.w);
  *(ushort4*)(out + i) = o;
}

// ---------- head-split kernels ----------
__global__ __launch_bounds__(256) void split_qk_kernel(const float* __restrict__ src,
    u16* __restrict__ qh, u16* __restrict__ kh)
{
  const int n = blockIdx.x * 256 + threadIdx.x;  // 0..2047
  const int m = blockIdx.y;                      // 0..4095
  const float v = src[(size_t)m * 3072 + n];
  const int which = n >> 10, r = n & 1023, h = r >> 6, d = r & 63;
  const int b = m >> 10, s = m & 1023;
  const size_t o = ((size_t)((b * 16 + h) * 1024 + s)) * 64 + d;
  if (which == 0) qh[o] = f2bf(v * 0.125f);
  else            kh[o] = f2bf(v);
}
__global__ __launch_bounds__(256) void split_q_kernel(const float* __restrict__ src, u16* __restrict__ qh) {
  const int n = blockIdx.x * 256 + threadIdx.x;
  const int m = blockIdx.y;
  const int h = n >> 6, d = n & 63, b = m >> 10, s = m & 1023;
  qh[((size_t)((b * 16 + h) * 1024 + s)) * 64 + d] = f2bf(src[(size_t)m * 1024 + n] * 0.125f);
}
__global__ __launch_bounds__(256) void split_k_kernel(const float* __restrict__ src, u16* __restrict__ kh) {
  const int n = blockIdx.x * 256 + threadIdx.x;
  const int m = blockIdx.y;
  const int h = n >> 6, d = n & 63, b = m >> 10, s = m & 1023;
  kh[((size_t)((b * 16 + h) * 1024 + s)) * 64 + d] = f2bf(src[(size_t)m * 2048 + n]);
}
__global__ __launch_bounds__(256) void vtrans_kernel(const float* __restrict__ src,
    int src_ld, int col_off, u16* __restrict__ vht)
{
  __shared__ float t[32][33];
  const int z = blockIdx.z, b = z >> 4, h = z & 15;
  const int s0 = blockIdx.y * 32, d0 = blockIdx.x * 32;
  const int tx = threadIdx.x & 31, ty = threadIdx.x >> 5;
#pragma unroll
  for (int r = ty; r < 32; r += 8)
    t[r][tx] = src[(size_t)(b * 1024 + s0 + r) * src_ld + col_off + h * 64 + d0 + tx];
  __syncthreads();
#pragma unroll
  for (int r = ty; r < 32; r += 8)
    vht[((size_t)z * 64 + d0 + r) * 1024 + s0 + tx] = f2bf(t[tx][r]);
}

// ---------- workspace layout (bytes) ----------
constexpr size_t WT_QKV    = 0;
constexpr size_t WT_ATTN_O = WT_QKV    + 3072ULL * 1024 * 2;
constexpr size_t WT_Q      = WT_ATTN_O + 1024ULL * 1024 * 2;
constexpr size_t WT_KV     = WT_Q      + 1024ULL * 1024 * 2;
constexpr size_t WT_CA_O   = WT_KV     + 2048ULL * 1024 * 2;
constexpr size_t WT_FFN_IN = WT_CA_O   + 1024ULL * 1024 * 2;
constexpr size_t WT_FFN_OUT= WT_FFN_IN + 4096ULL * 1024 * 2;
constexpr size_t ENC_BF    = WT_FFN_OUT+ 4096ULL * 1024 * 2;
constexpr size_t XLN       = ENC_BF    + 4096ULL * 1024 * 2;
constexpr size_t QH        = XLN       + 4096ULL * 1024 * 2;
constexpr size_t KH        = QH        + 64ULL * 1024 * 64 * 2;
constexpr size_t VHT       = KH        + 64ULL * 1024 * 64 * 2;
constexpr size_t CTX       = VHT       + 64ULL * 1024 * 64 * 2;
constexpr size_t HBUF      = CTX       + 4096ULL * 1024 * 2;
constexpr size_t SCRATCH   = HBUF      + 4096ULL * 1024 * 4;

extern "C" void kernel_launch(void* const* d_in, const int* in_sizes, int n_in,
                              void* d_out, int out_size, void* d_ws, size_t ws_size,
                              hipStream_t stream) {
  const float* hidden   = (const float*)d_in[0];
  const float* enc      = (const float*)d_in[1];
  const float* encm     = (const float*)d_in[2];
  const float* ln1w = (const float*)d_in[4],  *ln1b = (const float*)d_in[5];
  const float* qkv_w = (const float*)d_in[6], *qkv_b = (const float*)d_in[7];
  const float* attn_o_w = (const float*)d_in[8], *attn_o_b = (const float*)d_in[9];
  const float* ln2w = (const float*)d_in[10], *ln2b = (const float*)d_in[11];
  const float* q_w = (const float*)d_in[12],  *q_b = (const float*)d_in[13];
  const float* kv_w = (const float*)d_in[14], *kv_b = (const float*)d_in[15];
  const float* ca_o_w = (const float*)d_in[16], *ca_o_b = (const float*)d_in[17];
  const float* ln3w = (const float*)d_in[18], *ln3b = (const float*)d_in[19];
  const float* ffn_in_w = (const float*)d_in[20], *ffn_in_b = (const float*)d_in[21];
  const float* ffn_out_w = (const float*)d_in[22], *ffn_out_b = (const float*)d_in[23];

  char* ws = (char*)d_ws;
  u16* wt_qkv    = (u16*)(ws + WT_QKV);
  u16* wt_attn_o = (u16*)(ws + WT_ATTN_O);
  u16* wt_q      = (u16*)(ws + WT_Q);
  u16* wt_kv     = (u16*)(ws + WT_KV);
  u16* wt_ca_o   = (u16*)(ws + WT_CA_O);
  u16* wt_ffn_in = (u16*)(ws + WT_FFN_IN);
  u16* wt_ffn_out= (u16*)(ws + WT_FFN_OUT);
  u16* enc_bf = (u16*)(ws + ENC_BF);
  u16* xln    = (u16*)(ws + XLN);
  u16* qh     = (u16*)(ws + QH);
  u16* kh     = (u16*)(ws + KH);
  u16* vht    = (u16*)(ws + VHT);
  u16* ctx    = (u16*)(ws + CTX);
  float* hF   = (float*)(ws + HBUF);
  float* scratch = (float*)(ws + SCRATCH);
  u16* ffn_mid   = (u16*)(ws + SCRATCH);   // overlays scratch (disjoint lifetime)

  // ---- weight conversion ----
  wconv_kernel<<<dim3(96, 32), 256, 0, stream>>>(qkv_w, wt_qkv, 1024, 3072);
  wconv_kernel<<<dim3(32, 32), 256, 0, stream>>>(attn_o_w, wt_attn_o, 1024, 1024);
  wconv_kernel<<<dim3(32, 32), 256, 0, stream>>>(q_w, wt_q, 1024, 1024);
  wconv_kernel<<<dim3(64, 32), 256, 0, stream>>>(kv_w, wt_kv, 1024, 2048);
  wconv_kernel<<<dim3(32, 32), 256, 0, stream>>>(ca_o_w, wt_ca_o, 1024, 1024);
  wconv_kernel<<<dim3(128, 32), 256, 0, stream>>>(ffn_in_w, wt_ffn_in, 1024, 4096);
  wconv_kernel<<<dim3(32, 128), 256, 0, stream>>>(ffn_out_w, wt_ffn_out, 4096, 1024);
  cvt_kernel<<<4096, 256, 0, stream>>>(enc, enc_bf);

  // ---- self-attention ----
  ln_kernel<<<4096, 256, 0, stream>>>(hidden, ln1w, ln1b, xln);
  gemm_nt<<<dim3(24, 32), 256, 0, stream>>>(xln, wt_qkv, qkv_b, nullptr,
      scratch, 3072, 4096, 3072, 1024, 0);
  split_qk_kernel<<<dim3(8, 4096), 256, 0, stream>>>(scratch, qh, kh);
  vtrans_kernel<<<dim3(2, 32, 64), 256, 0, stream>>>(scratch, 3072, 2048, vht);
  flash_attn<<<dim3(8, 64), 256, 0, stream>>>(qh, kh, vht, nullptr, ctx, 1);
  gemm_k128<<<dim3(8, 32), 256, 0, stream>>>(ctx, wt_attn_o, attn_o_b, hidden,
      hF, 1024, 4096, 1024, 1024, 0);

  // ---- cross-attention ----
  ln_kernel<<<4096, 256, 0, stream>>>(hF, ln2w, ln2b, xln);
  gemm_k128<<<dim3(8, 32), 256, 0, stream>>>(xln, wt_q, q_b, nullptr,
      scratch, 1024, 4096, 1024, 1024, 0);
  split_q_kernel<<<dim3(4, 4096), 256, 0, stream>>>(scratch, qh);
  gemm_k128<<<dim3(16, 32), 256, 0, stream>>>(enc_bf, wt_kv, kv_b, nullptr,
      scratch, 2048, 4096, 2048, 1024, 0);
  split_k_kernel<<<dim3(4, 4096), 256, 0, stream>>>(scratch, kh);
  vtrans_kernel<<<dim3(2, 32, 64), 256, 0, stream>>>(scratch, 2048, 1024, vht);
  flash_attn<<<dim3(8, 64), 256, 0, stream>>>(qh, kh, vht, encm, ctx, 0);
  gemm_k128<<<dim3(8, 32), 256, 0, stream>>>(ctx, wt_ca_o, ca_o_b, hF,
      hF, 1024, 4096, 1024, 1024, 0);   // in-place residual: same-thread read/write

  // ---- FFN ----
  ln_kernel<<<4096, 256, 0, stream>>>(hF, ln3w, ln3b, xln);
  gemm_nt<<<dim3(32, 32), 256, 0, stream>>>(xln, wt_ffn_in, ffn_in_b, nullptr,
      ffn_mid, 4096, 4096, 4096, 1024, 2);
  gemm_k128<<<dim3(8, 32), 256, 0, stream>>>(ffn_mid, wt_ffn_out, ffn_out_b, hF,
      (float*)d_out, 1024, 4096, 1024, 4096, 0);
}

// Round 4
// 730.619 us; speedup vs baseline: 1.4585x; 1.4585x over previous
//
#include <hip/hip_runtime.h>
#include <cstdint>
#include <cstddef>

typedef unsigned short u16;
typedef __bf16 bf16x8 __attribute__((ext_vector_type(8)));
typedef float f32x4 __attribute__((ext_vector_type(4)));

// ---------- helpers ----------
__device__ __forceinline__ u16 f2bf(float f) {            // round-to-nearest-even
  unsigned u = __float_as_uint(f);
  u += 0x7fffu + ((u >> 16) & 1u);
  return (u16)(u >> 16);
}

__device__ __forceinline__ float block_sum(float v, float* sbuf, int tid) {
#pragma unroll
  for (int off = 1; off < 64; off <<= 1) v += __shfl_xor(v, off, 64);
  if ((tid & 63) == 0) sbuf[tid >> 6] = v;
  __syncthreads();
  v = sbuf[0] + sbuf[1] + sbuf[2] + sbuf[3];
  __syncthreads();
  return v;
}

// async global->LDS, 16B per lane; LDS dest = wave-uniform base + lane*16.
__device__ __forceinline__ void gld16(const void* g, void* l) {
  __builtin_amdgcn_global_load_lds((const __attribute__((address_space(1))) void*)g,
                                   (__attribute__((address_space(3))) void*)l,
                                   16, 0, 0);
}

// ---------- big-grid NT GEMM (128x128 tile, BK=32, gld16 staging) ----------
// mode 0: fp32 out + bias; mode 2: bf16 out = gelu(acc+bias)
__global__ __launch_bounds__(256) void gemm_nt(
    const u16* __restrict__ A, const u16* __restrict__ B,
    const float* __restrict__ bias,
    void* __restrict__ out, int ldc, int N, int K, int mode)
{
  __shared__ __align__(16) u16 As[128 * 32];
  __shared__ __align__(16) u16 Bs[128 * 32];
  const int tid = threadIdx.x;
  const int m0 = blockIdx.y * 128, n0 = blockIdx.x * 128;
  const int lane = tid & 63, wave = tid >> 6;
  const int l15 = lane & 15, g = (lane >> 4) & 3;
  const int wm = (wave >> 1) * 64, wn = (wave & 1) * 64;

  const int c0 = tid, c1 = tid + 256;
  const int ar0 = c0 >> 2, ak0 = (c0 & 3) * 8;
  const int ar1 = c1 >> 2, ak1 = (c1 & 3) * 8;
  const size_t aoff0 = (size_t)(m0 + ar0) * K + ak0;
  const size_t aoff1 = (size_t)(m0 + ar1) * K + ak1;
  const size_t boff0 = (size_t)(n0 + ar0) * K + ak0;
  const size_t boff1 = (size_t)(n0 + ar1) * K + ak1;

  f32x4 acc[4][4] = {};

  for (int k0 = 0; k0 < K; k0 += 32) {
    gld16(A + aoff0 + k0, As + (size_t)c0 * 8);
    gld16(A + aoff1 + k0, As + (size_t)c1 * 8);
    gld16(B + boff0 + k0, Bs + (size_t)c0 * 8);
    gld16(B + boff1 + k0, Bs + (size_t)c1 * 8);
    __syncthreads();
    bf16x8 af[4], bg[4];
#pragma unroll
    for (int i = 0; i < 4; i++) {
      af[i] = *(const bf16x8*)(As + (wm + i * 16 + l15) * 32 + g * 8);
      bg[i] = *(const bf16x8*)(Bs + (wn + i * 16 + l15) * 32 + g * 8);
    }
#pragma unroll
    for (int i = 0; i < 4; i++)
#pragma unroll
      for (int j = 0; j < 4; j++)
        acc[i][j] = __builtin_amdgcn_mfma_f32_16x16x32_bf16(af[i], bg[j], acc[i][j], 0, 0, 0);
    __syncthreads();
  }

  float* outF = (float*)out;
  u16* outU = (u16*)out;
#pragma unroll
  for (int i = 0; i < 4; i++) {
#pragma unroll
    for (int j = 0; j < 4; j++) {
      const int col = n0 + wn + j * 16 + l15;
#pragma unroll
      for (int r = 0; r < 4; r++) {
        const int gm = m0 + wm + i * 16 + g * 4 + r;
        const size_t idx = (size_t)gm * ldc + col;
        float v = acc[i][j][r] + bias[col];
        if (mode == 0) {
          outF[idx] = v;
        } else {
          v = 0.5f * v * (1.0f + erff(v * 0.70710678118654752f));
          outU[idx] = f2bf(v);
        }
      }
    }
  }
}

// ---------- split-K NT GEMM (M=4096, N=1024 fixed; S=gridDim.z splits) ----------
// partial[z][m][n] fp32, no bias. Same proven BK=32 gld16 body (no prefetch regs).
__global__ __launch_bounds__(256) void gemm_splitk(
    const u16* __restrict__ A, const u16* __restrict__ B,
    float* __restrict__ part, int K, int Klen)
{
  __shared__ __align__(16) u16 As[128 * 32];
  __shared__ __align__(16) u16 Bs[128 * 32];
  const int tid = threadIdx.x;
  const int m0 = blockIdx.y * 128, n0 = blockIdx.x * 128;
  const int kstart = blockIdx.z * Klen;
  float* outP = part + (size_t)blockIdx.z * (4096ULL * 1024);
  const int lane = tid & 63, wave = tid >> 6;
  const int l15 = lane & 15, g = (lane >> 4) & 3;
  const int wm = (wave >> 1) * 64, wn = (wave & 1) * 64;

  const int c0 = tid, c1 = tid + 256;
  const int ar0 = c0 >> 2, ak0 = (c0 & 3) * 8;
  const int ar1 = c1 >> 2, ak1 = (c1 & 3) * 8;
  const size_t aoff0 = (size_t)(m0 + ar0) * K + ak0;
  const size_t aoff1 = (size_t)(m0 + ar1) * K + ak1;
  const size_t boff0 = (size_t)(n0 + ar0) * K + ak0;
  const size_t boff1 = (size_t)(n0 + ar1) * K + ak1;

  f32x4 acc[4][4] = {};

  for (int k0 = kstart; k0 < kstart + Klen; k0 += 32) {
    gld16(A + aoff0 + k0, As + (size_t)c0 * 8);
    gld16(A + aoff1 + k0, As + (size_t)c1 * 8);
    gld16(B + boff0 + k0, Bs + (size_t)c0 * 8);
    gld16(B + boff1 + k0, Bs + (size_t)c1 * 8);
    __syncthreads();
    bf16x8 af[4], bg[4];
#pragma unroll
    for (int i = 0; i < 4; i++) {
      af[i] = *(const bf16x8*)(As + (wm + i * 16 + l15) * 32 + g * 8);
      bg[i] = *(const bf16x8*)(Bs + (wn + i * 16 + l15) * 32 + g * 8);
    }
#pragma unroll
    for (int i = 0; i < 4; i++)
#pragma unroll
      for (int j = 0; j < 4; j++)
        acc[i][j] = __builtin_amdgcn_mfma_f32_16x16x32_bf16(af[i], bg[j], acc[i][j], 0, 0, 0);
    __syncthreads();
  }

#pragma unroll
  for (int i = 0; i < 4; i++)
#pragma unroll
    for (int j = 0; j < 4; j++) {
      const int col = n0 + wn + j * 16 + l15;
#pragma unroll
      for (int r = 0; r < 4; r++) {
        const int gm = m0 + wm + i * 16 + g * 4 + r;
        outP[(size_t)gm * 1024 + col] = acc[i][j][r];
      }
    }
}

// ---------- fused flash attention, per-wave row ownership (R3, kept) ----------
__global__ __launch_bounds__(256, 2) void flash_attn(
    const u16* __restrict__ qh, const u16* __restrict__ kh, const u16* __restrict__ vht,
    const float* __restrict__ emask, u16* __restrict__ ctx, int causal)
{
  __shared__ __align__(16) u16 sK[128 * 72];
  __shared__ __align__(16) u16 sV[64 * 136];
  __shared__ __align__(16) u16 sP[128 * 136];

  const int tid = threadIdx.x, lane = tid & 63, wave = tid >> 6;
  const int l15 = lane & 15, g = (lane >> 4) & 3;
  const int z = blockIdx.y, b = z >> 4, h = z & 15;
  const int m0 = blockIdx.x * 128;
  const int r0 = wave * 32;

  bf16x8 qf[2][2];
  {
    const u16* qz = qh + ((size_t)z * 1024 + m0 + r0 + l15) * 64 + g * 8;
#pragma unroll
    for (int i2 = 0; i2 < 2; ++i2)
#pragma unroll
      for (int kc = 0; kc < 2; ++kc)
        qf[i2][kc] = *(const bf16x8*)(qz + (size_t)i2 * 16 * 64 + kc * 32);
  }

  float m_i[2][4], l_i[2][4];
#pragma unroll
  for (int i2 = 0; i2 < 2; ++i2)
#pragma unroll
    for (int r = 0; r < 4; ++r) { m_i[i2][r] = -1.0e30f; l_i[i2][r] = 0.0f; }

  f32x4 o[2][4] = {};
  const int tmax = causal ? m0 : 896;

  ulong2 kreg[4], vreg[4];
  {
    const u16* kb_ = kh + (size_t)z * 65536;
    const u16* vb_ = vht + (size_t)z * 65536;
#pragma unroll
    for (int i = 0; i < 4; ++i) {
      const int q = tid + i * 256;
      kreg[i] = *(const ulong2*)(kb_ + (size_t)(q >> 3) * 64 + (q & 7) * 8);
      vreg[i] = *(const ulong2*)(vb_ + (size_t)(q >> 4) * 1024 + (q & 15) * 8);
    }
  }

  for (int t0 = 0; t0 <= tmax; t0 += 128) {
    __syncthreads();
#pragma unroll
    for (int i = 0; i < 4; ++i) {
      const int q = tid + i * 256;
      *(ulong2*)(sK + (q >> 3) * 72 + (q & 7) * 8) = kreg[i];
      *(ulong2*)(sV + (q >> 4) * 136 + (q & 15) * 8) = vreg[i];
    }
    __syncthreads();
    if (t0 + 128 <= tmax) {
      const u16* kb_ = kh + (size_t)z * 65536 + (size_t)(t0 + 128) * 64;
      const u16* vb_ = vht + (size_t)z * 65536 + (t0 + 128);
#pragma unroll
      for (int i = 0; i < 4; ++i) {
        const int q = tid + i * 256;
        kreg[i] = *(const ulong2*)(kb_ + (size_t)(q >> 3) * 64 + (q & 7) * 8);
        vreg[i] = *(const ulong2*)(vb_ + (size_t)(q >> 4) * 1024 + (q & 15) * 8);
      }
    }

    f32x4 sa[2][8] = {};
#pragma unroll
    for (int kc = 0; kc < 2; ++kc) {
      bf16x8 bg[8];
#pragma unroll
      for (int jn = 0; jn < 8; ++jn)
        bg[jn] = *(const bf16x8*)(sK + (jn * 16 + l15) * 72 + kc * 32 + g * 8);
#pragma unroll
      for (int i2 = 0; i2 < 2; ++i2)
#pragma unroll
        for (int jn = 0; jn < 8; ++jn)
          sa[i2][jn] = __builtin_amdgcn_mfma_f32_16x16x32_bf16(qf[i2][kc], bg[jn], sa[i2][jn], 0, 0, 0);
    }

    if (causal) {
      if (t0 == m0) {
#pragma unroll
        for (int i2 = 0; i2 < 2; ++i2)
#pragma unroll
          for (int jn = 0; jn < 8; ++jn) {
            const int col = jn * 16 + l15;
#pragma unroll
            for (int r = 0; r < 4; ++r) {
              const int row = r0 + i2 * 16 + g * 4 + r;
              if (col > row) sa[i2][jn][r] = -3.0e38f;
            }
          }
      }
    } else {
#pragma unroll
      for (int jn = 0; jn < 8; ++jn) {
        const float mv = emask[(size_t)b * 1024 + t0 + jn * 16 + l15];
#pragma unroll
        for (int i2 = 0; i2 < 2; ++i2)
#pragma unroll
          for (int r = 0; r < 4; ++r) sa[i2][jn][r] += mv;
      }
    }

    float alpha[2][4];
#pragma unroll
    for (int i2 = 0; i2 < 2; ++i2)
#pragma unroll
      for (int r = 0; r < 4; ++r) {
        float v = sa[i2][0][r];
#pragma unroll
        for (int jn = 1; jn < 8; ++jn) v = fmaxf(v, sa[i2][jn][r]);
        v = fmaxf(v, __shfl_xor(v, 1, 64));
        v = fmaxf(v, __shfl_xor(v, 2, 64));
        v = fmaxf(v, __shfl_xor(v, 4, 64));
        v = fmaxf(v, __shfl_xor(v, 8, 64));
        const float mo = m_i[i2][r];
        const float mn = fmaxf(mo, v);
        m_i[i2][r] = mn;
        alpha[i2][r] = __expf(mo - mn);
        float s = 0.0f;
#pragma unroll
        for (int jn = 0; jn < 8; ++jn) {
          const float p = __expf(sa[i2][jn][r] - mn);
          s += p;
          sP[(r0 + i2 * 16 + g * 4 + r) * 136 + jn * 16 + l15] = f2bf(p);
        }
        s += __shfl_xor(s, 1, 64);
        s += __shfl_xor(s, 2, 64);
        s += __shfl_xor(s, 4, 64);
        s += __shfl_xor(s, 8, 64);
        l_i[i2][r] = alpha[i2][r] * l_i[i2][r] + s;
      }

#pragma unroll
    for (int i2 = 0; i2 < 2; ++i2)
#pragma unroll
      for (int jn = 0; jn < 4; ++jn)
#pragma unroll
        for (int r = 0; r < 4; ++r)
          o[i2][jn][r] *= alpha[i2][r];

    asm volatile("s_waitcnt lgkmcnt(0)" ::: "memory");
#pragma unroll
    for (int kc = 0; kc < 4; ++kc) {
      bf16x8 pa[2], vb[4];
#pragma unroll
      for (int i2 = 0; i2 < 2; ++i2)
        pa[i2] = *(const bf16x8*)(sP + (r0 + i2 * 16 + l15) * 136 + kc * 32 + g * 8);
#pragma unroll
      for (int jn = 0; jn < 4; ++jn)
        vb[jn] = *(const bf16x8*)(sV + (jn * 16 + l15) * 136 + kc * 32 + g * 8);
#pragma unroll
      for (int i2 = 0; i2 < 2; ++i2)
#pragma unroll
        for (int jn = 0; jn < 4; ++jn)
          o[i2][jn] = __builtin_amdgcn_mfma_f32_16x16x32_bf16(pa[i2], vb[jn], o[i2][jn], 0, 0, 0);
    }
  }

#pragma unroll
  for (int i2 = 0; i2 < 2; ++i2)
#pragma unroll
    for (int r = 0; r < 4; ++r) {
      const float inv = 1.0f / l_i[i2][r];
      const size_t base = ((size_t)(b * 1024 + m0 + r0 + i2 * 16 + g * 4 + r)) * 1024 + h * 64;
#pragma unroll
      for (int jn = 0; jn < 4; ++jn)
        ctx[base + jn * 16 + l15] = f2bf(o[i2][jn][r] * inv);
    }
}

// ---------- layernorm (row=1024, fp32 in) -> bf16 ----------
__global__ __launch_bounds__(256) void ln_kernel(const float* __restrict__ x,
    const float* __restrict__ w, const float* __restrict__ b, u16* __restrict__ out)
{
  __shared__ float sbuf[4];
  const int row = blockIdx.x, tid = threadIdx.x;
  const float4 v = *(const float4*)(x + (size_t)row * 1024 + tid * 4);
  float s = block_sum(v.x + v.y + v.z + v.w, sbuf, tid);
  const float u = s * (1.0f / 1024.0f);
  const float d0 = v.x - u, d1 = v.y - u, d2 = v.z - u, d3 = v.w - u;
  float sq = block_sum(d0 * d0 + d1 * d1 + d2 * d2 + d3 * d3, sbuf, tid);
  const float rstd = rsqrtf(sq * (1.0f / 1024.0f) + 1e-12f);
  const int c = tid * 4;
  ushort4 o;
  o.x = f2bf(w[c + 0] * d0 * rstd + b[c + 0]);
  o.y = f2bf(w[c + 1] * d1 * rstd + b[c + 1]);
  o.z = f2bf(w[c + 2] * d2 * rstd + b[c + 2]);
  o.w = f2bf(w[c + 3] * d3 * rstd + b[c + 3]);
  *(ushort4*)(out + (size_t)row * 1024 + c) = o;
}

// ---------- fused: h = p0+p1+bias+res; hOut=h; xln=LN(h) ----------
__global__ __launch_bounds__(256) void ln_red_kernel(
    const float* __restrict__ p0, const float* __restrict__ p1,
    const float* __restrict__ bias, const float* __restrict__ res,
    const float* __restrict__ w, const float* __restrict__ b,
    float* __restrict__ hOut, u16* __restrict__ xln)
{
  __shared__ float sbuf[4];
  const int row = blockIdx.x, tid = threadIdx.x;
  const size_t off = (size_t)row * 1024 + tid * 4;
  const int c = tid * 4;
  const float4 a0 = *(const float4*)(p0 + off);
  const float4 a1 = *(const float4*)(p1 + off);
  const float4 bs = *(const float4*)(bias + c);
  const float4 rs = *(const float4*)(res + off);
  float4 v;
  v.x = a0.x + a1.x + bs.x + rs.x;
  v.y = a0.y + a1.y + bs.y + rs.y;
  v.z = a0.z + a1.z + bs.z + rs.z;
  v.w = a0.w + a1.w + bs.w + rs.w;
  *(float4*)(hOut + off) = v;
  float s = block_sum(v.x + v.y + v.z + v.w, sbuf, tid);
  const float u = s * (1.0f / 1024.0f);
  const float d0 = v.x - u, d1 = v.y - u, d2 = v.z - u, d3 = v.w - u;
  float sq = block_sum(d0 * d0 + d1 * d1 + d2 * d2 + d3 * d3, sbuf, tid);
  const float rstd = rsqrtf(sq * (1.0f / 1024.0f) + 1e-12f);
  ushort4 o;
  o.x = f2bf(w[c + 0] * d0 * rstd + b[c + 0]);
  o.y = f2bf(w[c + 1] * d1 * rstd + b[c + 1]);
  o.z = f2bf(w[c + 2] * d2 * rstd + b[c + 2]);
  o.w = f2bf(w[c + 3] * d3 * rstd + b[c + 3]);
  *(ushort4*)(xln + off) = o;
}

// ---------- reduce q partials -> qh bf16 split-head layout, scaled 1/8 ----------
__global__ __launch_bounds__(256) void reduce_q_kernel(
    const float* __restrict__ p0, const float* __restrict__ p1,
    const float* __restrict__ bias, u16* __restrict__ qh)
{
  const int m = blockIdx.x, tid = threadIdx.x;
  const size_t off = (size_t)m * 1024 + tid * 4;
  const int n = tid * 4, h = n >> 6, d = n & 63;
  const int b = m >> 10, s = m & 1023;
  const float4 a0 = *(const float4*)(p0 + off);
  const float4 a1 = *(const float4*)(p1 + off);
  const float4 bs = *(const float4*)(bias + n);
  ushort4 o;
  o.x = f2bf((a0.x + a1.x + bs.x) * 0.125f);
  o.y = f2bf((a0.y + a1.y + bs.y) * 0.125f);
  o.z = f2bf((a0.z + a1.z + bs.z) * 0.125f);
  o.w = f2bf((a0.w + a1.w + bs.w) * 0.125f);
  *(ushort4*)(qh + ((size_t)((b * 16 + h) * 1024 + s)) * 64 + d) = o;
}

// ---------- reduce ffn_out partials + bias + res -> d_out fp32 ----------
__global__ __launch_bounds__(256) void reduce_out_kernel(
    const float* __restrict__ p0, const float* __restrict__ p1,
    const float* __restrict__ bias, const float* __restrict__ res,
    float* __restrict__ out)
{
  const int m = blockIdx.x, tid = threadIdx.x;
  const size_t off = (size_t)m * 1024 + tid * 4;
  const int c = tid * 4;
  const float4 a0 = *(const float4*)(p0 + off);
  const float4 a1 = *(const float4*)(p1 + off);
  const float4 bs = *(const float4*)(bias + c);
  const float4 rs = *(const float4*)(res + off);
  float4 v;
  v.x = a0.x + a1.x + bs.x + rs.x;
  v.y = a0.y + a1.y + bs.y + rs.y;
  v.z = a0.z + a1.z + bs.z + rs.z;
  v.w = a0.w + a1.w + bs.w + rs.w;
  *(float4*)(out + off) = v;
}

// ---------- weight fp32[K,N] -> bf16 transposed [N,K] ----------
__global__ __launch_bounds__(256) void wconv_kernel(const float* __restrict__ w,
    u16* __restrict__ wt, int K, int N)
{
  __shared__ float t[32][33];
  const int n0 = blockIdx.x * 32, k0 = blockIdx.y * 32;
  const int tx = threadIdx.x & 31, ty = threadIdx.x >> 5;
#pragma unroll
  for (int r = ty; r < 32; r += 8) t[r][tx] = w[(size_t)(k0 + r) * N + n0 + tx];
  __syncthreads();
#pragma unroll
  for (int r = ty; r < 32; r += 8) wt[(size_t)(n0 + r) * K + k0 + tx] = f2bf(t[tx][r]);
}

// ---------- fp32 -> bf16 elementwise ----------
__global__ __launch_bounds__(256) void cvt_kernel(const float* __restrict__ in, u16* __restrict__ out) {
  const size_t i = ((size_t)blockIdx.x * 256 + threadIdx.x) * 4;
  const float4 v = *(const float4*)(in + i);
  ushort4 o; o.x = f2bf(v.x); o.y = f2bf(v.y); o.z = f2bf(v.z); o.w = f2bf(v.w);
  *(ushort4*)(out + i) = o;
}

// ---------- head-split kernels ----------
__global__ __launch_bounds__(256) void split_qk_kernel(const float* __restrict__ src,
    u16* __restrict__ qh, u16* __restrict__ kh)
{
  const int n = blockIdx.x * 256 + threadIdx.x;  // 0..2047
  const int m = blockIdx.y;                      // 0..4095
  const float v = src[(size_t)m * 3072 + n];
  const int which = n >> 10, r = n & 1023, h = r >> 6, d = r & 63;
  const int b = m >> 10, s = m & 1023;
  const size_t o = ((size_t)((b * 16 + h) * 1024 + s)) * 64 + d;
  if (which == 0) qh[o] = f2bf(v * 0.125f);
  else            kh[o] = f2bf(v);
}
__global__ __launch_bounds__(256) void split_k_kernel(const float* __restrict__ src, u16* __restrict__ kh) {
  const int n = blockIdx.x * 256 + threadIdx.x;
  const int m = blockIdx.y;
  const int h = n >> 6, d = n & 63, b = m >> 10, s = m & 1023;
  kh[((size_t)((b * 16 + h) * 1024 + s)) * 64 + d] = f2bf(src[(size_t)m * 2048 + n]);
}
__global__ __launch_bounds__(256) void vtrans_kernel(const float* __restrict__ src,
    int src_ld, int col_off, u16* __restrict__ vht)
{
  __shared__ float t[32][33];
  const int z = blockIdx.z, b = z >> 4, h = z & 15;
  const int s0 = blockIdx.y * 32, d0 = blockIdx.x * 32;
  const int tx = threadIdx.x & 31, ty = threadIdx.x >> 5;
#pragma unroll
  for (int r = ty; r < 32; r += 8)
    t[r][tx] = src[(size_t)(b * 1024 + s0 + r) * src_ld + col_off + h * 64 + d0 + tx];
  __syncthreads();
#pragma unroll
  for (int r = ty; r < 32; r += 8)
    vht[((size_t)z * 64 + d0 + r) * 1024 + s0 + tx] = f2bf(t[tx][r]);
}

// ---------- workspace layout (bytes) ----------
constexpr size_t WT_QKV    = 0;
constexpr size_t WT_ATTN_O = WT_QKV    + 3072ULL * 1024 * 2;
constexpr size_t WT_Q      = WT_ATTN_O + 1024ULL * 1024 * 2;
constexpr size_t WT_KV     = WT_Q      + 1024ULL * 1024 * 2;
constexpr size_t WT_CA_O   = WT_KV     + 2048ULL * 1024 * 2;
constexpr size_t WT_FFN_IN = WT_CA_O   + 1024ULL * 1024 * 2;
constexpr size_t WT_FFN_OUT= WT_FFN_IN + 4096ULL * 1024 * 2;
constexpr size_t ENC_BF    = WT_FFN_OUT+ 4096ULL * 1024 * 2;
constexpr size_t XLN       = ENC_BF    + 4096ULL * 1024 * 2;
constexpr size_t QH        = XLN       + 4096ULL * 1024 * 2;   // 32MB window QH..CTX also
constexpr size_t KH        = QH        + 64ULL * 1024 * 64 * 2; //   doubles as ffn_out partials
constexpr size_t VHT       = KH        + 64ULL * 1024 * 64 * 2;
constexpr size_t CTX       = VHT       + 64ULL * 1024 * 64 * 2;
constexpr size_t HBUF      = CTX       + 4096ULL * 1024 * 2;
constexpr size_t SCRATCH   = HBUF      + 4096ULL * 1024 * 4;   // 48 MB multi-use

extern "C" void kernel_launch(void* const* d_in, const int* in_sizes, int n_in,
                              void* d_out, int out_size, void* d_ws, size_t ws_size,
                              hipStream_t stream) {
  const float* hidden   = (const float*)d_in[0];
  const float* enc      = (const float*)d_in[1];
  const float* encm     = (const float*)d_in[2];
  const float* ln1w = (const float*)d_in[4],  *ln1b = (const float*)d_in[5];
  const float* qkv_w = (const float*)d_in[6], *qkv_b = (const float*)d_in[7];
  const float* attn_o_w = (const float*)d_in[8], *attn_o_b = (const float*)d_in[9];
  const float* ln2w = (const float*)d_in[10], *ln2b = (const float*)d_in[11];
  const float* q_w = (const float*)d_in[12],  *q_b = (const float*)d_in[13];
  const float* kv_w = (const float*)d_in[14], *kv_b = (const float*)d_in[15];
  const float* ca_o_w = (const float*)d_in[16], *ca_o_b = (const float*)d_in[17];
  const float* ln3w = (const float*)d_in[18], *ln3b = (const float*)d_in[19];
  const float* ffn_in_w = (const float*)d_in[20], *ffn_in_b = (const float*)d_in[21];
  const float* ffn_out_w = (const float*)d_in[22], *ffn_out_b = (const float*)d_in[23];

  char* ws = (char*)d_ws;
  u16* wt_qkv    = (u16*)(ws + WT_QKV);
  u16* wt_attn_o = (u16*)(ws + WT_ATTN_O);
  u16* wt_q      = (u16*)(ws + WT_Q);
  u16* wt_kv     = (u16*)(ws + WT_KV);
  u16* wt_ca_o   = (u16*)(ws + WT_CA_O);
  u16* wt_ffn_in = (u16*)(ws + WT_FFN_IN);
  u16* wt_ffn_out= (u16*)(ws + WT_FFN_OUT);
  u16* enc_bf = (u16*)(ws + ENC_BF);
  u16* xln    = (u16*)(ws + XLN);
  u16* qh     = (u16*)(ws + QH);
  u16* kh     = (u16*)(ws + KH);
  u16* vht    = (u16*)(ws + VHT);
  u16* ctx    = (u16*)(ws + CTX);
  float* hF   = (float*)(ws + HBUF);
  float* scratch = (float*)(ws + SCRATCH);
  float* sp0 = scratch;                                   // split-K partial 0 (16 MB)
  float* sp1 = (float*)(ws + SCRATCH + 16ULL * 1024 * 1024);
  float* fp0 = (float*)(ws + QH);                          // ffn_out partials (dead QH..CTX)
  float* fp1 = (float*)(ws + QH + 16ULL * 1024 * 1024);
  u16* ffn_mid = (u16*)(ws + SCRATCH);                     // bf16 32 MB (after ca_o consumed)

  // ---- weight conversion ----
  wconv_kernel<<<dim3(96, 32), 256, 0, stream>>>(qkv_w, wt_qkv, 1024, 3072);
  wconv_kernel<<<dim3(32, 32), 256, 0, stream>>>(attn_o_w, wt_attn_o, 1024, 1024);
  wconv_kernel<<<dim3(32, 32), 256, 0, stream>>>(q_w, wt_q, 1024, 1024);
  wconv_kernel<<<dim3(64, 32), 256, 0, stream>>>(kv_w, wt_kv, 1024, 2048);
  wconv_kernel<<<dim3(32, 32), 256, 0, stream>>>(ca_o_w, wt_ca_o, 1024, 1024);
  wconv_kernel<<<dim3(128, 32), 256, 0, stream>>>(ffn_in_w, wt_ffn_in, 1024, 4096);
  wconv_kernel<<<dim3(32, 128), 256, 0, stream>>>(ffn_out_w, wt_ffn_out, 4096, 1024);
  cvt_kernel<<<4096, 256, 0, stream>>>(enc, enc_bf);

  // ---- self-attention ----
  ln_kernel<<<4096, 256, 0, stream>>>(hidden, ln1w, ln1b, xln);
  gemm_nt<<<dim3(24, 32), 256, 0, stream>>>(xln, wt_qkv, qkv_b,
      scratch, 3072, 3072, 1024, 0);                       // fp32 [4096,3072] uses all 48MB
  split_qk_kernel<<<dim3(8, 4096), 256, 0, stream>>>(scratch, qh, kh);
  vtrans_kernel<<<dim3(2, 32, 64), 256, 0, stream>>>(scratch, 3072, 2048, vht);
  flash_attn<<<dim3(8, 64), 256, 0, stream>>>(qh, kh, vht, nullptr, ctx, 1);
  gemm_splitk<<<dim3(8, 32, 2), 256, 0, stream>>>(ctx, wt_attn_o, sp0, 1024, 512);
  ln_red_kernel<<<4096, 256, 0, stream>>>(sp0, sp1, attn_o_b, hidden, ln2w, ln2b, hF, xln);

  // ---- cross-attention ----
  gemm_splitk<<<dim3(8, 32, 2), 256, 0, stream>>>(xln, wt_q, sp0, 1024, 512);
  reduce_q_kernel<<<4096, 256, 0, stream>>>(sp0, sp1, q_b, qh);
  gemm_nt<<<dim3(16, 32), 256, 0, stream>>>(enc_bf, wt_kv, kv_b,
      scratch, 2048, 2048, 1024, 0);                       // fp32 [4096,2048] 32MB
  split_k_kernel<<<dim3(4, 4096), 256, 0, stream>>>(scratch, kh);
  vtrans_kernel<<<dim3(2, 32, 64), 256, 0, stream>>>(scratch, 2048, 1024, vht);
  flash_attn<<<dim3(8, 64), 256, 0, stream>>>(qh, kh, vht, encm, ctx, 0);
  gemm_splitk<<<dim3(8, 32, 2), 256, 0, stream>>>(ctx, wt_ca_o, sp0, 1024, 512);
  ln_red_kernel<<<4096, 256, 0, stream>>>(sp0, sp1, ca_o_b, hF, ln3w, ln3b, hF, xln);

  // ---- FFN ----
  gemm_nt<<<dim3(32, 32), 256, 0, stream>>>(xln, wt_ffn_in, ffn_in_b,
      ffn_mid, 4096, 4096, 1024, 2);                       // bf16 32MB at scratch
  gemm_splitk<<<dim3(8, 32, 2), 256, 0, stream>>>(ffn_mid, wt_ffn_out, fp0, 4096, 2048);
  reduce_out_kernel<<<4096, 256, 0, stream>>>(fp0, fp1, ffn_out_b, hF, (float*)d_out);
}

// Round 5
// 661.265 us; speedup vs baseline: 1.6115x; 1.1049x over previous
//
#include <hip/hip_runtime.h>
#include <cstdint>
#include <cstddef>

typedef unsigned short u16;
typedef __bf16 bf16x8 __attribute__((ext_vector_type(8)));
typedef float f32x4 __attribute__((ext_vector_type(4)));

// ---------- helpers ----------
__device__ __forceinline__ u16 f2bf(float f) {            // round-to-nearest-even
  unsigned u = __float_as_uint(f);
  u += 0x7fffu + ((u >> 16) & 1u);
  return (u16)(u >> 16);
}

__device__ __forceinline__ float block_sum(float v, float* sbuf, int tid) {
#pragma unroll
  for (int off = 1; off < 64; off <<= 1) v += __shfl_xor(v, off, 64);
  if ((tid & 63) == 0) sbuf[tid >> 6] = v;
  __syncthreads();
  v = sbuf[0] + sbuf[1] + sbuf[2] + sbuf[3];
  __syncthreads();
  return v;
}

// async global->LDS, 16B per lane; LDS dest = wave-uniform base + lane*16.
__device__ __forceinline__ void gld16(const void* g, void* l) {
  __builtin_amdgcn_global_load_lds((const __attribute__((address_space(1))) void*)g,
                                   (__attribute__((address_space(3))) void*)l,
                                   16, 0, 0);
}

// Tiled K layout: kt[z][tile][c=d/8][t=0..127][j=d%8]  (16KB per tile = MFMA B-frag image)
// Tiled V layout: vt[z][tile][tc=t/8][d=0..63][j=t%8]  (16KB per tile)

// ---------- big-grid NT GEMM (128x128 tile, BK=32, gld16 staging) ----------
// M=4096. mode 0: Q->out0 (qh bf16, *0.125, head-split)
//         mode 1: QKV->qh(out0)/kt(out1)/vh(out2)
//         mode 2: bf16 gelu(acc+bias) -> out0 row-major ld N
//         mode 3: KV->kt(out1)/vh(out2)
__global__ __launch_bounds__(256) void gemm_nt(
    const u16* __restrict__ A, const u16* __restrict__ B,
    const float* __restrict__ bias,
    void* __restrict__ out0, void* __restrict__ out1, void* __restrict__ out2,
    int N, int K, int mode)
{
  __shared__ __align__(16) u16 As[128 * 32];
  __shared__ __align__(16) u16 Bs[128 * 32];
  const int tid = threadIdx.x;
  const int m0 = blockIdx.y * 128, n0 = blockIdx.x * 128;
  const int lane = tid & 63, wave = tid >> 6;
  const int l15 = lane & 15, g = (lane >> 4) & 3;
  const int wm = (wave >> 1) * 64, wn = (wave & 1) * 64;

  const int c0 = tid, c1 = tid + 256;
  const int ar0 = c0 >> 2, ak0 = (c0 & 3) * 8;
  const int ar1 = c1 >> 2, ak1 = (c1 & 3) * 8;
  const size_t aoff0 = (size_t)(m0 + ar0) * K + ak0;
  const size_t aoff1 = (size_t)(m0 + ar1) * K + ak1;
  const size_t boff0 = (size_t)(n0 + ar0) * K + ak0;
  const size_t boff1 = (size_t)(n0 + ar1) * K + ak1;

  f32x4 acc[4][4] = {};

  for (int k0 = 0; k0 < K; k0 += 32) {
    gld16(A + aoff0 + k0, As + (size_t)c0 * 8);
    gld16(A + aoff1 + k0, As + (size_t)c1 * 8);
    gld16(B + boff0 + k0, Bs + (size_t)c0 * 8);
    gld16(B + boff1 + k0, Bs + (size_t)c1 * 8);
    __syncthreads();
    bf16x8 af[4], bg[4];
#pragma unroll
    for (int i = 0; i < 4; i++) {
      af[i] = *(const bf16x8*)(As + (wm + i * 16 + l15) * 32 + g * 8);
      bg[i] = *(const bf16x8*)(Bs + (wn + i * 16 + l15) * 32 + g * 8);
    }
#pragma unroll
    for (int i = 0; i < 4; i++)
#pragma unroll
      for (int j = 0; j < 4; j++)
        acc[i][j] = __builtin_amdgcn_mfma_f32_16x16x32_bf16(af[i], bg[j], acc[i][j], 0, 0, 0);
    __syncthreads();
  }

#pragma unroll
  for (int i = 0; i < 4; i++) {
#pragma unroll
    for (int j = 0; j < 4; j++) {
      const int col = n0 + wn + j * 16 + l15;
      const int sec = (n0 + wn + j * 16) >> 10;        // wave-uniform section
#pragma unroll
      for (int r = 0; r < 4; r++) {
        const int gm = m0 + wm + i * 16 + g * 4 + r;
        float v = acc[i][j][r] + bias[col];
        if (mode == 2) {
          v = 0.5f * v * (1.0f + erff(v * 0.70710678118654752f));
          ((u16*)out0)[(size_t)gm * N + col] = f2bf(v);
        } else {
          const int tgt = (mode == 1) ? sec : (mode == 3 ? sec + 1 : 0);
          const int cl = col & 1023, h = cl >> 6, d = cl & 63;
          const int z = (gm >> 10) * 16 + h, s = gm & 1023;
          if (tgt == 0)
            ((u16*)out0)[((size_t)z * 1024 + s) * 64 + d] = f2bf(v * 0.125f);
          else if (tgt == 1)
            ((u16*)out1)[((((size_t)z * 8 + (s >> 7)) * 8 + (d >> 3)) * 128 + (s & 127)) * 8 + (d & 7)] = f2bf(v);
          else
            ((u16*)out2)[((size_t)z * 1024 + s) * 64 + d] = f2bf(v);
        }
      }
    }
  }
}

// ---------- split-K NT GEMM (M=4096, N=1024; partials fp32) ----------
__global__ __launch_bounds__(256) void gemm_splitk(
    const u16* __restrict__ A, const u16* __restrict__ B,
    float* __restrict__ part, int K, int Klen)
{
  __shared__ __align__(16) u16 As[128 * 32];
  __shared__ __align__(16) u16 Bs[128 * 32];
  const int tid = threadIdx.x;
  const int m0 = blockIdx.y * 128, n0 = blockIdx.x * 128;
  const int kstart = blockIdx.z * Klen;
  float* outP = part + (size_t)blockIdx.z * (4096ULL * 1024);
  const int lane = tid & 63, wave = tid >> 6;
  const int l15 = lane & 15, g = (lane >> 4) & 3;
  const int wm = (wave >> 1) * 64, wn = (wave & 1) * 64;

  const int c0 = tid, c1 = tid + 256;
  const int ar0 = c0 >> 2, ak0 = (c0 & 3) * 8;
  const int ar1 = c1 >> 2, ak1 = (c1 & 3) * 8;
  const size_t aoff0 = (size_t)(m0 + ar0) * K + ak0;
  const size_t aoff1 = (size_t)(m0 + ar1) * K + ak1;
  const size_t boff0 = (size_t)(n0 + ar0) * K + ak0;
  const size_t boff1 = (size_t)(n0 + ar1) * K + ak1;

  f32x4 acc[4][4] = {};

  for (int k0 = kstart; k0 < kstart + Klen; k0 += 32) {
    gld16(A + aoff0 + k0, As + (size_t)c0 * 8);
    gld16(A + aoff1 + k0, As + (size_t)c1 * 8);
    gld16(B + boff0 + k0, Bs + (size_t)c0 * 8);
    gld16(B + boff1 + k0, Bs + (size_t)c1 * 8);
    __syncthreads();
    bf16x8 af[4], bg[4];
#pragma unroll
    for (int i = 0; i < 4; i++) {
      af[i] = *(const bf16x8*)(As + (wm + i * 16 + l15) * 32 + g * 8);
      bg[i] = *(const bf16x8*)(Bs + (wn + i * 16 + l15) * 32 + g * 8);
    }
#pragma unroll
    for (int i = 0; i < 4; i++)
#pragma unroll
      for (int j = 0; j < 4; j++)
        acc[i][j] = __builtin_amdgcn_mfma_f32_16x16x32_bf16(af[i], bg[j], acc[i][j], 0, 0, 0);
    __syncthreads();
  }

#pragma unroll
  for (int i = 0; i < 4; i++)
#pragma unroll
    for (int j = 0; j < 4; j++) {
      const int col = n0 + wn + j * 16 + l15;
#pragma unroll
      for (int r = 0; r < 4; r++) {
        const int gm = m0 + wm + i * 16 + g * 4 + r;
        outP[(size_t)gm * 1024 + col] = acc[i][j][r];
      }
    }
}

// ---------- flash attention v3: gld16 tiled staging, 64-col chunks ----------
// qh [64][1024][64] (scaled), kt/vt tiled (see above), ctx [4][1024][1024] bf16.
// grid (8 m-tiles, 64 z), 256 thr. LDS 50.4 KB. 2 barriers/iter.
__global__ __launch_bounds__(256, 2) void flash_attn(
    const u16* __restrict__ qh, const u16* __restrict__ kt, const u16* __restrict__ vt,
    const float* __restrict__ emask, u16* __restrict__ ctx, int causal)
{
  __shared__ __align__(16) u16 sK[8192];      // tile image [c][t][8]   16 KB
  __shared__ __align__(16) u16 sV[8192];      // tile image [tc][d][8]  16 KB
  __shared__ __align__(16) u16 sP[128 * 72];  // P chunk [row][64+8pad] 18.4 KB

  const int tid = threadIdx.x, lane = tid & 63, wave = tid >> 6;
  const int l15 = lane & 15, g = (lane >> 4) & 3;
  const int z = blockIdx.y, b = z >> 4, h = z & 15;
  const int m0 = blockIdx.x * 128;
  const int r0 = wave * 32;

  // persistent Q fragments (rows r0..r0+31)
  bf16x8 qf[2][2];
  {
    const u16* qz = qh + ((size_t)z * 1024 + m0 + r0 + l15) * 64 + g * 8;
#pragma unroll
    for (int i2 = 0; i2 < 2; ++i2)
#pragma unroll
      for (int kc = 0; kc < 2; ++kc)
        qf[i2][kc] = *(const bf16x8*)(qz + (size_t)i2 * 16 * 64 + kc * 32);
  }

  float m_i[2][4], l_i[2][4];
#pragma unroll
  for (int i2 = 0; i2 < 2; ++i2)
#pragma unroll
    for (int r = 0; r < 4; ++r) { m_i[i2][r] = -1.0e30f; l_i[i2][r] = 0.0f; }

  f32x4 o[2][4] = {};
  const int tmax = causal ? m0 : 896;

  for (int t0 = 0; t0 <= tmax; t0 += 128) {
    const u16* ktile = kt + ((size_t)z * 8 + (t0 >> 7)) * 8192;
    const u16* vtile = vt + ((size_t)z * 8 + (t0 >> 7)) * 8192;
    __syncthreads();                          // prev iter done with sK/sV
#pragma unroll
    for (int i = 0; i < 4; ++i) {
      const int off = (wave * 4 + i) * 512 + lane * 8;   // u16 units, 16B/lane
      gld16(ktile + off, sK + off);
      gld16(vtile + off, sV + off);
    }
    __syncthreads();                          // vmcnt(0) drain + barrier: staging visible

#pragma unroll
    for (int ci = 0; ci < 2; ++ci) {
      if (causal && t0 == m0 && ci * 64 > r0 + 31) continue;   // whole chunk masked

      // ---- S chunk = Q K^T : rows [r0,r0+32) x cols [ci*64, ci*64+64) ----
      f32x4 sa[2][4] = {};
#pragma unroll
      for (int kc = 0; kc < 2; ++kc) {
        bf16x8 bg[4];
#pragma unroll
        for (int jn = 0; jn < 4; ++jn)
          bg[jn] = *(const bf16x8*)(sK + ((kc * 4 + g) * 128 + ci * 64 + jn * 16 + l15) * 8);
#pragma unroll
        for (int i2 = 0; i2 < 2; ++i2)
#pragma unroll
          for (int jn = 0; jn < 4; ++jn)
            sa[i2][jn] = __builtin_amdgcn_mfma_f32_16x16x32_bf16(qf[i2][kc], bg[jn], sa[i2][jn], 0, 0, 0);
      }

      // ---- mask ----
      if (causal) {
        if (t0 == m0 && ci * 64 + 63 > r0) {
#pragma unroll
          for (int i2 = 0; i2 < 2; ++i2)
#pragma unroll
            for (int jn = 0; jn < 4; ++jn) {
              const int col = ci * 64 + jn * 16 + l15;
#pragma unroll
              for (int r = 0; r < 4; ++r) {
                const int row = r0 + i2 * 16 + g * 4 + r;
                if (col > row) sa[i2][jn][r] = -3.0e38f;
              }
            }
        }
      } else {
#pragma unroll
        for (int jn = 0; jn < 4; ++jn) {
          const float mv = emask[(size_t)b * 1024 + t0 + ci * 64 + jn * 16 + l15];
#pragma unroll
          for (int i2 = 0; i2 < 2; ++i2)
#pragma unroll
            for (int r = 0; r < 4; ++r) sa[i2][jn][r] += mv;
        }
      }

      // ---- in-wave online softmax ----
      float alpha[2][4];
#pragma unroll
      for (int i2 = 0; i2 < 2; ++i2)
#pragma unroll
        for (int r = 0; r < 4; ++r) {
          const int rowl = r0 + i2 * 16 + g * 4 + r;
          float v = fmaxf(fmaxf(sa[i2][0][r], sa[i2][1][r]), fmaxf(sa[i2][2][r], sa[i2][3][r]));
          v = fmaxf(v, __shfl_xor(v, 1, 64));
          v = fmaxf(v, __shfl_xor(v, 2, 64));
          v = fmaxf(v, __shfl_xor(v, 4, 64));
          v = fmaxf(v, __shfl_xor(v, 8, 64));
          const float mo = m_i[i2][r];
          const float mn = fmaxf(mo, v);
          m_i[i2][r] = mn;
          alpha[i2][r] = __expf(mo - mn);
          float s = 0.0f;
#pragma unroll
          for (int jn = 0; jn < 4; ++jn) {
            const float p = __expf(sa[i2][jn][r] - mn);
            s += p;
            sP[rowl * 72 + jn * 16 + l15] = f2bf(p);
          }
          s += __shfl_xor(s, 1, 64);
          s += __shfl_xor(s, 2, 64);
          s += __shfl_xor(s, 4, 64);
          s += __shfl_xor(s, 8, 64);
          l_i[i2][r] = alpha[i2][r] * l_i[i2][r] + s;
        }

#pragma unroll
      for (int i2 = 0; i2 < 2; ++i2)
#pragma unroll
        for (int jn = 0; jn < 4; ++jn)
#pragma unroll
          for (int r = 0; r < 4; ++r)
            o[i2][jn][r] *= alpha[i2][r];

      asm volatile("s_waitcnt lgkmcnt(0)" ::: "memory");   // own P writes visible
      // ---- O += P V (own rows; no barrier) ----
#pragma unroll
      for (int kc2 = 0; kc2 < 2; ++kc2) {
        bf16x8 pa[2], vb[4];
#pragma unroll
        for (int i2 = 0; i2 < 2; ++i2)
          pa[i2] = *(const bf16x8*)(sP + (r0 + i2 * 16 + l15) * 72 + kc2 * 32 + g * 8);
#pragma unroll
        for (int jn = 0; jn < 4; ++jn)
          vb[jn] = *(const bf16x8*)(sV + ((ci * 8 + kc2 * 4 + g) * 64 + jn * 16 + l15) * 8);
#pragma unroll
        for (int i2 = 0; i2 < 2; ++i2)
#pragma unroll
          for (int jn = 0; jn < 4; ++jn)
            o[i2][jn] = __builtin_amdgcn_mfma_f32_16x16x32_bf16(pa[i2], vb[jn], o[i2][jn], 0, 0, 0);
      }
    }
  }

  // ---- epilogue: O / l, merged heads ----
#pragma unroll
  for (int i2 = 0; i2 < 2; ++i2)
#pragma unroll
    for (int r = 0; r < 4; ++r) {
      const float inv = 1.0f / l_i[i2][r];
      const size_t base = ((size_t)(b * 1024 + m0 + r0 + i2 * 16 + g * 4 + r)) * 1024 + h * 64;
#pragma unroll
      for (int jn = 0; jn < 4; ++jn)
        ctx[base + jn * 16 + l15] = f2bf(o[i2][jn][r] * inv);
    }
}

// ---------- layernorm (row=1024, fp32 in) -> bf16 ----------
__global__ __launch_bounds__(256) void ln_kernel(const float* __restrict__ x,
    const float* __restrict__ w, const float* __restrict__ b, u16* __restrict__ out)
{
  __shared__ float sbuf[4];
  const int row = blockIdx.x, tid = threadIdx.x;
  const float4 v = *(const float4*)(x + (size_t)row * 1024 + tid * 4);
  float s = block_sum(v.x + v.y + v.z + v.w, sbuf, tid);
  const float u = s * (1.0f / 1024.0f);
  const float d0 = v.x - u, d1 = v.y - u, d2 = v.z - u, d3 = v.w - u;
  float sq = block_sum(d0 * d0 + d1 * d1 + d2 * d2 + d3 * d3, sbuf, tid);
  const float rstd = rsqrtf(sq * (1.0f / 1024.0f) + 1e-12f);
  const int c = tid * 4;
  ushort4 o;
  o.x = f2bf(w[c + 0] * d0 * rstd + b[c + 0]);
  o.y = f2bf(w[c + 1] * d1 * rstd + b[c + 1]);
  o.z = f2bf(w[c + 2] * d2 * rstd + b[c + 2]);
  o.w = f2bf(w[c + 3] * d3 * rstd + b[c + 3]);
  *(ushort4*)(out + (size_t)row * 1024 + c) = o;
}

// ---------- fused: h = p0+p1+bias+res; hOut=h; xln=LN(h) ----------
__global__ __launch_bounds__(256) void ln_red_kernel(
    const float* __restrict__ p0, const float* __restrict__ p1,
    const float* __restrict__ bias, const float* __restrict__ res,
    const float* __restrict__ w, const float* __restrict__ b,
    float* __restrict__ hOut, u16* __restrict__ xln)
{
  __shared__ float sbuf[4];
  const int row = blockIdx.x, tid = threadIdx.x;
  const size_t off = (size_t)row * 1024 + tid * 4;
  const int c = tid * 4;
  const float4 a0 = *(const float4*)(p0 + off);
  const float4 a1 = *(const float4*)(p1 + off);
  const float4 bs = *(const float4*)(bias + c);
  const float4 rs = *(const float4*)(res + off);
  float4 v;
  v.x = a0.x + a1.x + bs.x + rs.x;
  v.y = a0.y + a1.y + bs.y + rs.y;
  v.z = a0.z + a1.z + bs.z + rs.z;
  v.w = a0.w + a1.w + bs.w + rs.w;
  *(float4*)(hOut + off) = v;
  float s = block_sum(v.x + v.y + v.z + v.w, sbuf, tid);
  const float u = s * (1.0f / 1024.0f);
  const float d0 = v.x - u, d1 = v.y - u, d2 = v.z - u, d3 = v.w - u;
  float sq = block_sum(d0 * d0 + d1 * d1 + d2 * d2 + d3 * d3, sbuf, tid);
  const float rstd = rsqrtf(sq * (1.0f / 1024.0f) + 1e-12f);
  ushort4 o;
  o.x = f2bf(w[c + 0] * d0 * rstd + b[c + 0]);
  o.y = f2bf(w[c + 1] * d1 * rstd + b[c + 1]);
  o.z = f2bf(w[c + 2] * d2 * rstd + b[c + 2]);
  o.w = f2bf(w[c + 3] * d3 * rstd + b[c + 3]);
  *(ushort4*)(xln + off) = o;
}

// ---------- reduce ffn_out partials + bias + res -> d_out fp32 ----------
__global__ __launch_bounds__(256) void reduce_out_kernel(
    const float* __restrict__ p0, const float* __restrict__ p1,
    const float* __restrict__ bias, const float* __restrict__ res,
    float* __restrict__ out)
{
  const int m = blockIdx.x, tid = threadIdx.x;
  const size_t off = (size_t)m * 1024 + tid * 4;
  const int c = tid * 4;
  const float4 a0 = *(const float4*)(p0 + off);
  const float4 a1 = *(const float4*)(p1 + off);
  const float4 bs = *(const float4*)(bias + c);
  const float4 rs = *(const float4*)(res + off);
  float4 v;
  v.x = a0.x + a1.x + bs.x + rs.x;
  v.y = a0.y + a1.y + bs.y + rs.y;
  v.z = a0.z + a1.z + bs.z + rs.z;
  v.w = a0.w + a1.w + bs.w + rs.w;
  *(float4*)(out + off) = v;
}

// ---------- weight fp32[K,N] -> bf16 transposed [N,K] ----------
__global__ __launch_bounds__(256) void wconv_kernel(const float* __restrict__ w,
    u16* __restrict__ wt, int K, int N)
{
  __shared__ float t[32][33];
  const int n0 = blockIdx.x * 32, k0 = blockIdx.y * 32;
  const int tx = threadIdx.x & 31, ty = threadIdx.x >> 5;
#pragma unroll
  for (int r = ty; r < 32; r += 8) t[r][tx] = w[(size_t)(k0 + r) * N + n0 + tx];
  __syncthreads();
#pragma unroll
  for (int r = ty; r < 32; r += 8) wt[(size_t)(n0 + r) * K + k0 + tx] = f2bf(t[tx][r]);
}

// ---------- fp32 -> bf16 elementwise ----------
__global__ __launch_bounds__(256) void cvt_kernel(const float* __restrict__ in, u16* __restrict__ out) {
  const size_t i = ((size_t)blockIdx.x * 256 + threadIdx.x) * 4;
  const float4 v = *(const float4*)(in + i);
  ushort4 o; o.x = f2bf(v.x); o.y = f2bf(v.y); o.z = f2bf(v.z); o.w = f2bf(v.w);
  *(ushort4*)(out + i) = o;
}

// ---------- vh [z][t][d] bf16 -> vt tiled [z][tile][tc][d][8] ----------
__global__ __launch_bounds__(256) void vtrans_kernel(const u16* __restrict__ vh,
    u16* __restrict__ vt)
{
  __shared__ u16 sT[128 * 68];
  const int tile = blockIdx.x, z = blockIdx.y, tid = threadIdx.x;
  const u16* src = vh + ((size_t)z * 1024 + tile * 128) * 64;
#pragma unroll
  for (int k = 0; k < 8; ++k) {
    const int u = tid + k * 256;            // 2048 ushort4 units
    const int tl = u >> 4, dq = u & 15;
    *(ushort4*)(sT + tl * 68 + dq * 4) = *(const ushort4*)(src + (size_t)tl * 64 + dq * 4);
  }
  __syncthreads();
  u16* dst = vt + ((size_t)z * 8 + tile) * 8192;
#pragma unroll
  for (int kk = 0; kk < 4; ++kk) {
    const int tc = (tid >> 6) + kk * 4, d = tid & 63;
    ushort4 o1, o2;
    o1.x = sT[(tc * 8 + 0) * 68 + d]; o1.y = sT[(tc * 8 + 1) * 68 + d];
    o1.z = sT[(tc * 8 + 2) * 68 + d]; o1.w = sT[(tc * 8 + 3) * 68 + d];
    o2.x = sT[(tc * 8 + 4) * 68 + d]; o2.y = sT[(tc * 8 + 5) * 68 + d];
    o2.z = sT[(tc * 8 + 6) * 68 + d]; o2.w = sT[(tc * 8 + 7) * 68 + d];
    u16* p = dst + ((size_t)tc * 64 + d) * 8;
    *(ushort4*)(p) = o1;
    *(ushort4*)(p + 4) = o2;
  }
}

// ---------- workspace layout (bytes) ----------
constexpr size_t WT_QKV    = 0;
constexpr size_t WT_ATTN_O = WT_QKV    + 3072ULL * 1024 * 2;
constexpr size_t WT_Q      = WT_ATTN_O + 1024ULL * 1024 * 2;
constexpr size_t WT_KV     = WT_Q      + 1024ULL * 1024 * 2;
constexpr size_t WT_CA_O   = WT_KV     + 2048ULL * 1024 * 2;
constexpr size_t WT_FFN_IN = WT_CA_O   + 1024ULL * 1024 * 2;
constexpr size_t WT_FFN_OUT= WT_FFN_IN + 4096ULL * 1024 * 2;
constexpr size_t ENC_BF    = WT_FFN_OUT+ 4096ULL * 1024 * 2;
constexpr size_t XLN       = ENC_BF    + 4096ULL * 1024 * 2;
constexpr size_t QH        = XLN       + 4096ULL * 1024 * 2;
constexpr size_t KT        = QH        + 64ULL * 1024 * 64 * 2;
constexpr size_t VH        = KT        + 64ULL * 1024 * 64 * 2;
constexpr size_t VT        = VH        + 64ULL * 1024 * 64 * 2;
constexpr size_t CTX       = VT        + 64ULL * 1024 * 64 * 2;
constexpr size_t HBUF      = CTX       + 4096ULL * 1024 * 2;
constexpr size_t SP0       = HBUF      + 4096ULL * 1024 * 4;
constexpr size_t SP1       = SP0       + 4096ULL * 1024 * 4;
constexpr size_t FFN_MID   = SP1       + 4096ULL * 1024 * 4;   // bf16 32 MB
// total = FFN_MID + 32 MB = 168 MB

extern "C" void kernel_launch(void* const* d_in, const int* in_sizes, int n_in,
                              void* d_out, int out_size, void* d_ws, size_t ws_size,
                              hipStream_t stream) {
  const float* hidden   = (const float*)d_in[0];
  const float* enc      = (const float*)d_in[1];
  const float* encm     = (const float*)d_in[2];
  const float* ln1w = (const float*)d_in[4],  *ln1b = (const float*)d_in[5];
  const float* qkv_w = (const float*)d_in[6], *qkv_b = (const float*)d_in[7];
  const float* attn_o_w = (const float*)d_in[8], *attn_o_b = (const float*)d_in[9];
  const float* ln2w = (const float*)d_in[10], *ln2b = (const float*)d_in[11];
  const float* q_w = (const float*)d_in[12],  *q_b = (const float*)d_in[13];
  const float* kv_w = (const float*)d_in[14], *kv_b = (const float*)d_in[15];
  const float* ca_o_w = (const float*)d_in[16], *ca_o_b = (const float*)d_in[17];
  const float* ln3w = (const float*)d_in[18], *ln3b = (const float*)d_in[19];
  const float* ffn_in_w = (const float*)d_in[20], *ffn_in_b = (const float*)d_in[21];
  const float* ffn_out_w = (const float*)d_in[22], *ffn_out_b = (const float*)d_in[23];

  char* ws = (char*)d_ws;
  u16* wt_qkv    = (u16*)(ws + WT_QKV);
  u16* wt_attn_o = (u16*)(ws + WT_ATTN_O);
  u16* wt_q      = (u16*)(ws + WT_Q);
  u16* wt_kv     = (u16*)(ws + WT_KV);
  u16* wt_ca_o   = (u16*)(ws + WT_CA_O);
  u16* wt_ffn_in = (u16*)(ws + WT_FFN_IN);
  u16* wt_ffn_out= (u16*)(ws + WT_FFN_OUT);
  u16* enc_bf = (u16*)(ws + ENC_BF);
  u16* xln    = (u16*)(ws + XLN);
  u16* qh     = (u16*)(ws + QH);
  u16* kt     = (u16*)(ws + KT);
  u16* vh     = (u16*)(ws + VH);
  u16* vt     = (u16*)(ws + VT);
  u16* ctx    = (u16*)(ws + CTX);
  float* hF   = (float*)(ws + HBUF);
  float* sp0  = (float*)(ws + SP0);
  float* sp1  = (float*)(ws + SP1);
  u16* ffn_mid = (u16*)(ws + FFN_MID);

  // ---- weight conversion ----
  wconv_kernel<<<dim3(96, 32), 256, 0, stream>>>(qkv_w, wt_qkv, 1024, 3072);
  wconv_kernel<<<dim3(32, 32), 256, 0, stream>>>(attn_o_w, wt_attn_o, 1024, 1024);
  wconv_kernel<<<dim3(32, 32), 256, 0, stream>>>(q_w, wt_q, 1024, 1024);
  wconv_kernel<<<dim3(64, 32), 256, 0, stream>>>(kv_w, wt_kv, 1024, 2048);
  wconv_kernel<<<dim3(32, 32), 256, 0, stream>>>(ca_o_w, wt_ca_o, 1024, 1024);
  wconv_kernel<<<dim3(128, 32), 256, 0, stream>>>(ffn_in_w, wt_ffn_in, 1024, 4096);
  wconv_kernel<<<dim3(32, 128), 256, 0, stream>>>(ffn_out_w, wt_ffn_out, 4096, 1024);
  cvt_kernel<<<4096, 256, 0, stream>>>(enc, enc_bf);

  // ---- self-attention ----
  ln_kernel<<<4096, 256, 0, stream>>>(hidden, ln1w, ln1b, xln);
  gemm_nt<<<dim3(24, 32), 256, 0, stream>>>(xln, wt_qkv, qkv_b,
      qh, kt, vh, 3072, 1024, 1);                          // QKV direct bf16 epilogue
  vtrans_kernel<<<dim3(8, 64), 256, 0, stream>>>(vh, vt);
  flash_attn<<<dim3(8, 64), 256, 0, stream>>>(qh, kt, vt, nullptr, ctx, 1);
  gemm_splitk<<<dim3(8, 32, 2), 256, 0, stream>>>(ctx, wt_attn_o, sp0, 1024, 512);
  ln_red_kernel<<<4096, 256, 0, stream>>>(sp0, sp1, attn_o_b, hidden, ln2w, ln2b, hF, xln);

  // ---- cross-attention ----
  gemm_nt<<<dim3(8, 32), 256, 0, stream>>>(xln, wt_q, q_b,
      qh, nullptr, nullptr, 1024, 1024, 0);                // Q direct (scaled)
  gemm_nt<<<dim3(16, 32), 256, 0, stream>>>(enc_bf, wt_kv, kv_b,
      nullptr, kt, vh, 2048, 1024, 3);                     // KV direct
  vtrans_kernel<<<dim3(8, 64), 256, 0, stream>>>(vh, vt);
  flash_attn<<<dim3(8, 64), 256, 0, stream>>>(qh, kt, vt, encm, ctx, 0);
  gemm_splitk<<<dim3(8, 32, 2), 256, 0, stream>>>(ctx, wt_ca_o, sp0, 1024, 512);
  ln_red_kernel<<<4096, 256, 0, stream>>>(sp0, sp1, ca_o_b, hF, ln3w, ln3b, hF, xln);

  // ---- FFN ----
  gemm_nt<<<dim3(32, 32), 256, 0, stream>>>(xln, wt_ffn_in, ffn_in_b,
      ffn_mid, nullptr, nullptr, 4096, 1024, 2);           // GELU bf16
  gemm_splitk<<<dim3(8, 32, 2), 256, 0, stream>>>(ffn_mid, wt_ffn_out, sp0, 4096, 2048);
  reduce_out_kernel<<<4096, 256, 0, stream>>>(sp0, sp1, ffn_out_b, hF, (float*)d_out);
}